// Round 9
// baseline (25.173 us; speedup 1.0000x reference)
//
#include <hip/hip_runtime.h>

#define NOUT 10
#define SIG_DIM 584   // 8 + 64 + 512
#define TPAD 132      // padded T-stride: (i*TPAD)%32 = 4i -> conflict-free cols

typedef float float8v __attribute__((ext_vector_type(8)));

__device__ __forceinline__ float rdlane(float x, int lane) {
    return __int_as_float(__builtin_amdgcn_readlane(__float_as_int(x), lane));
}

// ---- Prepass: dX = X[t+1]-X[t] (row 127 zeroed) into d_ws, coalesced. ----
__global__ __launch_bounds__(256) void dx_prepass(const float* __restrict__ X,
                                                  float* __restrict__ dX)
{
    const int t = blockIdx.x * 256 + threadIdx.x;   // float4 index, 524288 total
    const int r = (t >> 1) & 127;                   // row within batch
    const float4* X4 = reinterpret_cast<const float4*>(X);
    const float4 a = X4[t];
    float4 d = make_float4(0.f, 0.f, 0.f, 0.f);
    if (r < 127) {
        const float4 c = X4[t + 2];                 // next row, same cols
        d = make_float4(c.x - a.x, c.y - a.y, c.z - a.z, c.w - a.w);
    }
    reinterpret_cast<float4*>(dX)[t] = d;
}

// ---- Main: 1 wave per batch (r5 structure). Row broadcast via SGPR s_load
// from precomputed dX (SMEM pipe, zero VALU cost; v_fma takes 1 SGPR src).
// Per-lane dxi/dxj: transposed padded LDS columns (conflict-free).
// Per-step VALU: 8 fma + 7 update = 15 (was 23 with v_readlane broadcasts). ----
__global__ __launch_bounds__(256) void sig_main(
    const float* __restrict__ X, const float* __restrict__ dX,
    const float* __restrict__ W, const float* __restrict__ bias,
    float* __restrict__ out)
{
    __shared__ float s_dxT[4][8 * TPAD];

    const int tid = threadIdx.x;
    const int w = tid >> 6;
    const int l = tid & 63;
    const int i = l >> 3;
    const int j = l & 7;
    const int b = blockIdx.x * 4 + w;
    const int bu = __builtin_amdgcn_readfirstlane(b);   // force uniform -> s_load
    const float* dXb = dX + (size_t)bu * 1024;

    // Stage transposed dX columns for per-lane dxi/dxj reads.
    float* dxT = &s_dxT[w][0];
    const int cb = (l & 1) * 4;
    const int rl = l >> 1;
#pragma unroll
    for (int q = 0; q < 4; ++q) {
        const int r = q * 32 + rl;
        const float4 d = *reinterpret_cast<const float4*>(dXb + r * 8 + cb);
        dxT[(cb + 0) * TPAD + r] = d.x;
        dxT[(cb + 1) * TPAD + r] = d.y;
        dxT[(cb + 2) * TPAD + r] = d.z;
        dxT[(cb + 3) * TPAD + r] = d.w;
    }
    __syncthreads();

    float s3[8];
#pragma unroll
    for (int k = 0; k < 8; ++k) s3[k] = 0.f;
    float s2 = 0.f, s1i = 0.f;

    const float* icol = dxT + i * TPAD;
    const float* jcol = dxT + j * TPAD;
    const float8v* srow = reinterpret_cast<const float8v*>(dXb);  // uniform rows

#define STEP(T, DXI, DXJ)                                                     \
    {                                                                         \
        const float8v rr = srow[(T)];          /* s_load_dwordx8 (SMEM) */    \
        const float cc = (DXI) * (DXJ);                                       \
        const float uu = s1i * (DXJ);                                         \
        const float f  = fmaf(0.5f, uu, fmaf(1.0f / 6.0f, cc, s2));           \
        s3[0] = fmaf(f, rr[0], s3[0]);                                        \
        s3[1] = fmaf(f, rr[1], s3[1]);                                        \
        s3[2] = fmaf(f, rr[2], s3[2]);                                        \
        s3[3] = fmaf(f, rr[3], s3[3]);                                        \
        s3[4] = fmaf(f, rr[4], s3[4]);                                        \
        s3[5] = fmaf(f, rr[5], s3[5]);                                        \
        s3[6] = fmaf(f, rr[6], s3[6]);                                        \
        s3[7] = fmaf(f, rr[7], s3[7]);                                        \
        s2 = fmaf(0.5f, cc, s2 + uu);                                         \
        s1i += (DXI);                                                         \
    }

#define GROUP(T0)                                                             \
    {                                                                         \
        const float4 ic = *reinterpret_cast<const float4*>(icol + (T0));      \
        const float4 jc = *reinterpret_cast<const float4*>(jcol + (T0));      \
        STEP((T0) + 0, ic.x, jc.x)                                            \
        STEP((T0) + 1, ic.y, jc.y)                                            \
        STEP((T0) + 2, ic.z, jc.z)                                            \
        STEP((T0) + 3, ic.w, jc.w)                                            \
    }
#define G16(A) GROUP(A) GROUP((A) + 4) GROUP((A) + 8) GROUP((A) + 12)
    G16(0) G16(16) G16(32) G16(48) G16(64) G16(80) G16(96) G16(112)
#undef G16
#undef GROUP
#undef STEP

    // s1j in closed form (telescoping): X[127][j] - X[0][j].
    const float* Xb = X + (size_t)b * 1024;
    const float s1j = Xb[127 * 8 + j] - Xb[j];

    // Epilogue: out[b][o] = bias[o] + W[o][:] . sig[b][:]
    // sig layout: [0..7]=S1, [8+l]=S2[i][j], [72+l*8+k]=S3[i][j][k]
#pragma unroll
    for (int o = 0; o < NOUT; ++o) {
        const float* wrow = W + o * SIG_DIM;
        float part = s2 * wrow[8 + l];
        const float4 w0 = *reinterpret_cast<const float4*>(wrow + 72 + l * 8);
        const float4 w1 = *reinterpret_cast<const float4*>(wrow + 72 + l * 8 + 4);
        part = fmaf(s3[0], w0.x, part); part = fmaf(s3[1], w0.y, part);
        part = fmaf(s3[2], w0.z, part); part = fmaf(s3[3], w0.w, part);
        part = fmaf(s3[4], w1.x, part); part = fmaf(s3[5], w1.y, part);
        part = fmaf(s3[6], w1.z, part); part = fmaf(s3[7], w1.w, part);
        if (i == 0) part = fmaf(s1j, wrow[j], part);   // S1 contribution
#pragma unroll
        for (int off = 32; off > 0; off >>= 1) part += __shfl_xor(part, off);
        if (l == 0) out[b * NOUT + o] = part + bias[o];
    }
}

// ---- Fallback (r5-proven, 21.6 us) if ws_size is too small for dX. ----
__global__ __launch_bounds__(256) void sig_fallback(
    const float* __restrict__ X, const float* __restrict__ W,
    const float* __restrict__ bias, float* __restrict__ out)
{
    __shared__ float s_dxT[4][8 * TPAD];
    const int tid = threadIdx.x;
    const int w = tid >> 6;
    const int l = tid & 63;
    const int i = l >> 3;
    const int j = l & 7;
    const int b = blockIdx.x * 4 + w;
    const float* Xb = X + (size_t)b * 1024;
    float* dxT = &s_dxT[w][0];
    const int cb = (l & 1) * 4;
    const int rl = l >> 1;
    float4 dA, dB, dC, dD;
#define PREP(DQ, QQ)                                                          \
    {                                                                         \
        const int r = (QQ) * 32 + rl;                                         \
        const float* xr = Xb + r * 8 + cb;                                    \
        const float4 a  = *reinterpret_cast<const float4*>(xr);               \
        const float4 c4 = *reinterpret_cast<const float4*>(xr + (r < 127 ? 8 : 0)); \
        DQ.x = (r < 127) ? c4.x - a.x : 0.f;                                  \
        DQ.y = (r < 127) ? c4.y - a.y : 0.f;                                  \
        DQ.z = (r < 127) ? c4.z - a.z : 0.f;                                  \
        DQ.w = (r < 127) ? c4.w - a.w : 0.f;                                  \
        dxT[(cb + 0) * TPAD + r] = DQ.x;                                      \
        dxT[(cb + 1) * TPAD + r] = DQ.y;                                      \
        dxT[(cb + 2) * TPAD + r] = DQ.z;                                      \
        dxT[(cb + 3) * TPAD + r] = DQ.w;                                      \
    }
    PREP(dA, 0) PREP(dB, 1) PREP(dC, 2) PREP(dD, 3)
#undef PREP
    __syncthreads();
    float s3[8];
#pragma unroll
    for (int k = 0; k < 8; ++k) s3[k] = 0.f;
    float s2 = 0.f, s1i = 0.f, s1j = 0.f;
    const float* icol = dxT + i * TPAD;
    const float* jcol = dxT + j * TPAD;
#define STEP(DQ, LB, DXI, DXJ)                                                \
    {                                                                         \
        const float k0 = rdlane(DQ.x, (LB));                                  \
        const float k1 = rdlane(DQ.y, (LB));                                  \
        const float k2 = rdlane(DQ.z, (LB));                                  \
        const float k3 = rdlane(DQ.w, (LB));                                  \
        const float k4 = rdlane(DQ.x, (LB) + 1);                              \
        const float k5 = rdlane(DQ.y, (LB) + 1);                              \
        const float k6 = rdlane(DQ.z, (LB) + 1);                              \
        const float k7 = rdlane(DQ.w, (LB) + 1);                              \
        const float cc = (DXI) * (DXJ);                                       \
        const float uu = s1i * (DXJ);                                         \
        const float f  = fmaf(0.5f, uu, fmaf(1.0f / 6.0f, cc, s2));           \
        s3[0] = fmaf(f, k0, s3[0]);                                           \
        s3[1] = fmaf(f, k1, s3[1]);                                           \
        s3[2] = fmaf(f, k2, s3[2]);                                           \
        s3[3] = fmaf(f, k3, s3[3]);                                           \
        s3[4] = fmaf(f, k4, s3[4]);                                           \
        s3[5] = fmaf(f, k5, s3[5]);                                           \
        s3[6] = fmaf(f, k6, s3[6]);                                           \
        s3[7] = fmaf(f, k7, s3[7]);                                           \
        s2 = fmaf(0.5f, cc, s2 + uu);                                         \
        s1i += (DXI);                                                         \
        s1j += (DXJ);                                                         \
    }
#define SECTION(DQ, QQ)                                                       \
    for (int g = 0; g < 8; ++g) {                                             \
        const int t0 = (QQ) * 32 + g * 4;                                     \
        const float4 ic = *reinterpret_cast<const float4*>(icol + t0);        \
        const float4 jc = *reinterpret_cast<const float4*>(jcol + t0);        \
        const int lb = g * 8;                                                 \
        STEP(DQ, lb + 0, ic.x, jc.x)                                          \
        STEP(DQ, lb + 2, ic.y, jc.y)                                          \
        STEP(DQ, lb + 4, ic.z, jc.z)                                          \
        STEP(DQ, lb + 6, ic.w, jc.w)                                          \
    }
    SECTION(dA, 0) SECTION(dB, 1) SECTION(dC, 2) SECTION(dD, 3)
#undef SECTION
#undef STEP
#pragma unroll
    for (int o = 0; o < NOUT; ++o) {
        const float* wrow = W + o * SIG_DIM;
        float part = s2 * wrow[8 + l];
        const float4 w0 = *reinterpret_cast<const float4*>(wrow + 72 + l * 8);
        const float4 w1 = *reinterpret_cast<const float4*>(wrow + 72 + l * 8 + 4);
        part = fmaf(s3[0], w0.x, part); part = fmaf(s3[1], w0.y, part);
        part = fmaf(s3[2], w0.z, part); part = fmaf(s3[3], w0.w, part);
        part = fmaf(s3[4], w1.x, part); part = fmaf(s3[5], w1.y, part);
        part = fmaf(s3[6], w1.z, part); part = fmaf(s3[7], w1.w, part);
        if (i == 0) part = fmaf(s1j, wrow[j], part);
#pragma unroll
        for (int off = 32; off > 0; off >>= 1) part += __shfl_xor(part, off);
        if (l == 0) out[b * NOUT + o] = part + bias[o];
    }
}

extern "C" void kernel_launch(void* const* d_in, const int* in_sizes, int n_in,
                              void* d_out, int out_size, void* d_ws, size_t ws_size,
                              hipStream_t stream) {
    const float* X = (const float*)d_in[0];     // (2048, 128, 8)
    const float* W = (const float*)d_in[1];     // (10, 584)
    const float* bias = (const float*)d_in[2];  // (10,)
    float* out = (float*)d_out;                 // (2048, 10)
    const size_t need = 2048ull * 1024ull * sizeof(float);   // 8 MB dX
    if (ws_size >= need) {
        float* dX = (float*)d_ws;
        dx_prepass<<<dim3(2048), dim3(256), 0, stream>>>(X, dX);
        sig_main<<<dim3(512), dim3(256), 0, stream>>>(X, dX, W, bias, out);
    } else {
        sig_fallback<<<dim3(512), dim3(256), 0, stream>>>(X, W, bias, out);
    }
}